// Round 4
// baseline (1092.758 us; speedup 1.0000x reference)
//
#include <hip/hip_runtime.h>

// BNB 8-bit embedding dequant-on-gather — INSTRUMENTATION ROUND (R4).
// Identical math to R3, but the whole gather+dequant+store is repeated
// REPS=16x inside one dispatch (idempotent: writes the same output every
// rep). Purpose: our single-rep dispatch is <323us and never appears in
// the rocprof top-5 (which is wall-to-wall harness fill dispatches), so we
// have no FETCH/WRITE/hbm_gbps evidence for the kernel itself. 16 reps
// pushes the dispatch above the ~330us fills so it surfaces with counters.
// The asm memory clobber between reps prevents the compiler from hoisting
// the (const __restrict) gather loads out of the rep loop.
//
// out[t, d] = code[q_idx_flat[x[t]*1024 + d]] * absmax[x[t]/64, (x[t]%64)>>2]
// blk = (local*1024 + d)//4096 is constant over d -> scale scalar per token.

#define EMBED_DIM 1024
#define T_PER_BLOCK 8
#define REPS 16

typedef float vfloat4 __attribute__((ext_vector_type(4)));
typedef int   vint4   __attribute__((ext_vector_type(4)));

__global__ __launch_bounds__(256) void bnb8_embed_kernel(
    const int*   __restrict__ x,
    const int*   __restrict__ q_idx,    // [2000*64*1024] flat
    const float* __restrict__ absmax,   // [2000*16] flat
    const float* __restrict__ code,     // [256]
    float*       __restrict__ out,      // [n_tokens*1024]
    int n_tokens)
{
    __shared__ float code_lds[256];
    const int tid = threadIdx.x;        // 0..255
    code_lds[tid] = code[tid];

    const int tbase = blockIdx.x * T_PER_BLOCK;

    // Token ids + scales (wave-uniform -> scalar loads).
    int   xv[T_PER_BLOCK];
    float sc[T_PER_BLOCK];
#pragma unroll
    for (int t = 0; t < T_PER_BLOCK; ++t) {
        const int tok = tbase + t;
        xv[t] = (tok < n_tokens) ? x[tok] : 0;
    }
#pragma unroll
    for (int t = 0; t < T_PER_BLOCK; ++t) {
        sc[t] = absmax[(xv[t] >> 6) * 16 + ((xv[t] & 63) >> 2)];
    }

    __syncthreads();

    for (int rep = 0; rep < REPS; ++rep) {
        asm volatile("" ::: "memory");   // force re-issue of loads each rep

        vint4 q[T_PER_BLOCK];
#pragma unroll
        for (int t = 0; t < T_PER_BLOCK; ++t) {
            q[t] = ((const vint4*)(q_idx + (size_t)xv[t] * EMBED_DIM))[tid];
        }

#pragma unroll
        for (int t = 0; t < T_PER_BLOCK; ++t) {
            const int tok = tbase + t;
            if (tok < n_tokens) {
                vfloat4 v;
                v.x = code_lds[q[t].x] * sc[t];
                v.y = code_lds[q[t].y] * sc[t];
                v.z = code_lds[q[t].z] * sc[t];
                v.w = code_lds[q[t].w] * sc[t];
                __builtin_nontemporal_store(v, ((vfloat4*)(out + (size_t)tok * EMBED_DIM)) + tid);
            }
        }
    }
}

extern "C" void kernel_launch(void* const* d_in, const int* in_sizes, int n_in,
                              void* d_out, int out_size, void* d_ws, size_t ws_size,
                              hipStream_t stream) {
    const int*   x      = (const int*)d_in[0];    // [8*4096]
    const int*   q_idx  = (const int*)d_in[1];    // [2000,64,1024]
    const float* absmax = (const float*)d_in[2];  // [2000,16]
    const float* code   = (const float*)d_in[3];  // [256]
    float*       out    = (float*)d_out;          // [8,4096,1024] fp32

    const int n_tokens = in_sizes[0];             // 32768
    const int n_blocks = (n_tokens + T_PER_BLOCK - 1) / T_PER_BLOCK;
    bnb8_embed_kernel<<<n_blocks, 256, 0, stream>>>(x, q_idx, absmax, code, out, n_tokens);
}

// Round 5
// 632.057 us; speedup vs baseline: 1.7289x; 1.7289x over previous
//
#include <hip/hip_runtime.h>

// BNB 8-bit embedding dequant-on-gather — final (revert of R4 instrumentation).
// out[t, d] = code[q_idx_flat[x[t]*1024 + d]] * absmax[x[t]/64, (x[t]%64)>>2]
//
// blk = (local*1024 + d)//4096 is constant over d in [0,1024) because
// local*1024 is 1024-aligned and the span is exactly 1024 -> blk = local>>2.
// So scale is a single scalar per token (kills the per-element absmax gather).
//
// Evidence (R4, 16-rep instrumented run): kernel sustains 5.33 TB/s (85% of
// the 6.3 TB/s achievable HBM ceiling), VALUBusy 3.9%, MfmaUtil 0, LDS bank
// conflicts fully hidden. Single-shot kernel ~80us; bench total is dominated
// by ~554us of harness fill/restore overhead. R1 (1 tok/block) vs R3
// (8 tok/block + NT stores) benched 627 vs 634 — within noise; keeping the
// simplest, lowest-measured variant.

#define EMBED_DIM 1024

__global__ __launch_bounds__(256) void bnb8_embed_kernel(
    const int*   __restrict__ x,
    const int*   __restrict__ q_idx,    // [2000*64*1024] flat
    const float* __restrict__ absmax,   // [2000*16] flat
    const float* __restrict__ code,     // [256]
    float*       __restrict__ out)      // [n_tokens*1024]
{
    __shared__ float code_lds[256];
    const int tid = threadIdx.x;        // 0..255
    code_lds[tid] = code[tid];

    const int token = blockIdx.x;
    const int xv    = x[token];         // same-address broadcast across block
    const int local = xv & 63;
    const int chunk = xv >> 6;
    const float scale = absmax[chunk * 16 + (local >> 2)];
    __syncthreads();

    // Each thread: 16B vector load of 4 code indices, 4 LDS lookups, 16B store.
    const int4 q = ((const int4*)(q_idx + (size_t)xv * EMBED_DIM))[tid];
    float4 v;
    v.x = code_lds[q.x] * scale;
    v.y = code_lds[q.y] * scale;
    v.z = code_lds[q.z] * scale;
    v.w = code_lds[q.w] * scale;
    ((float4*)(out + (size_t)token * EMBED_DIM))[tid] = v;
}

extern "C" void kernel_launch(void* const* d_in, const int* in_sizes, int n_in,
                              void* d_out, int out_size, void* d_ws, size_t ws_size,
                              hipStream_t stream) {
    const int*   x      = (const int*)d_in[0];    // [8*4096]
    const int*   q_idx  = (const int*)d_in[1];    // [2000,64,1024]
    const float* absmax = (const float*)d_in[2];  // [2000,16]
    const float* code   = (const float*)d_in[3];  // [256]
    float*       out    = (float*)d_out;          // [8,4096,1024] fp32

    const int n_tokens = in_sizes[0];             // 32768
    bnb8_embed_kernel<<<n_tokens, 256, 0, stream>>>(x, q_idx, absmax, code, out);
}